// Round 20
// baseline (320.677 us; speedup 1.0000x reference)
//
#include <hip/hip_runtime.h>
#include <hip/hip_bf16.h>

typedef __hip_bfloat16 bf16;
typedef __bf16 bf16x8 __attribute__((ext_vector_type(8)));
typedef float  f32x4  __attribute__((ext_vector_type(4)));

#define N_NODES 50000
#define N_EDGES 400000
#define NT 3125    // N_NODES/16 row-tiles
#define HID 128
#define MSG 128

// Activation layouts (MFMA-fragment-tiled):
//   XT[t][kc 0..31][r 0..15][e 0..8)  -- x at kc 0..15, c at kc 16..31
//   HT[t][kc 0..15][r][e]             -- h (bf16, ping-pong HT0/HT1)
// Weights: Wsd_f[kc 0..31][j 0..255][8] and Wg[kc 0..47][j' 0..511][8],
// both LINEAR fragment layout -> B-frags read DIRECT from global (L2-hot).

// ---------------------------------------------------------------------------
// SD GEMM: SD[M,256] = [x|h] @ Wsd^T. BM=256, BN=64, 4 waves.
// Direct-global B frags; single barrier (epilogue C-tile). XCD grid (800).
// ---------------------------------------------------------------------------
__global__ __launch_bounds__(256, 4)
void gemm_sd_kernel(const bf16* __restrict__ XT,
                    const bf16* __restrict__ HT,
                    const bf16* __restrict__ W,      // [32][256][8] linear frag
                    bf16* __restrict__ O, int M) {
    constexpr int K = 256, J = 256;
    __shared__ __align__(16) bf16 Cs[256 * 64];      // 32KB C tile

    const int bid = blockIdx.x;
    const int mt  = (bid >> 5) * 8 + (bid & 7);      // m-tile 0..199
    const int bnt = (bid >> 3) & 3;
    if (mt * 256 >= M) return;                       // uniform
    const int bm = mt * 256;
    const int bn = bnt * 64;
    const int tid = threadIdx.x;

    const int w    = tid >> 6;
    const int lane = tid & 63;
    const int lr   = lane & 15;
    const int kg   = lane >> 4;
    const int mbase = bm + w * 64;

    int tile[4];
    #pragma unroll
    for (int fm = 0; fm < 4; ++fm) {
        int t = (mbase + fm * 16) >> 4;
        tile[fm] = (t < NT) ? t : NT - 1;            // OOB discarded at store
    }
    const bf16* Wb = W + ((size_t)kg * 256 + bn + lr) * 8;

    f32x4 acc[4][4] = {};

    #pragma unroll
    for (int k0 = 0; k0 < K; k0 += 32) {
        bf16x8 a[4];
        #pragma unroll
        for (int fm = 0; fm < 4; ++fm) {
            const bf16* ap = (k0 < 128)
                ? XT + ((size_t)tile[fm] * 32 + (k0 >> 3) + kg) * 128 + lr * 8
                : HT + ((size_t)tile[fm] * 16 + ((k0 - 128) >> 3) + kg) * 128 + lr * 8;
            a[fm] = *reinterpret_cast<const bf16x8*>(ap);
        }
        __builtin_amdgcn_s_setprio(1);
        #pragma unroll
        for (int fn = 0; fn < 4; ++fn) {
            bf16x8 b = *reinterpret_cast<const bf16x8*>(
                Wb + (((size_t)(k0 >> 3)) * 256 + fn * 16) * 8);
            #pragma unroll
            for (int fm = 0; fm < 4; ++fm)
                acc[fm][fn] = __builtin_amdgcn_mfma_f32_16x16x32_bf16(
                    a[fm], b, acc[fm][fn], 0, 0, 0);
        }
        __builtin_amdgcn_s_setprio(0);
    }

    // epilogue: C tile through LDS (swizzled) for coalesced 128B stores
    #pragma unroll
    for (int fn = 0; fn < 4; ++fn) {
        int col = fn * 16 + lr;
        #pragma unroll
        for (int fm = 0; fm < 4; ++fm) {
            int rbase = w * 64 + fm * 16 + kg * 4;
            #pragma unroll
            for (int r = 0; r < 4; ++r) {
                int row = rbase + r;
                int cs = ((((col >> 3) ^ ((row >> 2) & 7))) << 3) | (col & 7);
                Cs[row * 64 + cs] = __float2bfloat16(acc[fm][fn][r]);
            }
        }
    }
    __syncthreads();
    const int colblk = tid & 7;
    const int rbase_o = tid >> 3;
    #pragma unroll
    for (int it = 0; it < 8; ++it) {
        int row = it * 32 + rbase_o;
        int grow = bm + row;
        if (grow < M) {
            int g = (row >> 2) & 7;
            const float4 v = *reinterpret_cast<const float4*>(
                &Cs[row * 64 + ((colblk ^ g) << 3)]);
            *reinterpret_cast<float4*>(O + (size_t)grow * J + bn + colblk * 8) = v;
        }
    }
}

// ---------------------------------------------------------------------------
// Fused gates GEMM + GRU: barrier-free / LDS-free, XCD grid, chunk-skip,
// fragment-tiled A, bf16 hin, setprio. R20: __launch_bounds__(256,6) --
// VGPR cap 85 >= measured 64 (no spill), 6 blocks/CU (+50% latency hiding).
// ---------------------------------------------------------------------------
__device__ __forceinline__ float fast_sigmoid(float x) {
    return 1.0f / (1.0f + __expf(-x));
}
__device__ __forceinline__ float fast_tanh(float x) {
    float e = __expf(-2.0f * fabsf(x));
    float t = (1.0f - e) / (1.0f + e);
    return copysignf(t, x);
}

template <int FINAL>
__global__ __launch_bounds__(256, 6)
void gates_kernel(const bf16* __restrict__ XT,
                  const bf16* __restrict__ HT,     // tiled h (read)
                  const bf16* __restrict__ Wg,     // [48][512][8] linear
                  const float* __restrict__ bg,    // [512] fused bias
                  float* __restrict__ h_out,       // f32 out (FINAL)
                  bf16* __restrict__ HTout,        // tiled h out (non-final)
                  int M) {
    const int bid = blockIdx.x;
    const int mt  = (bid >> 6) * 8 + (bid & 7);   // m-tile 0..199
    const int q   = (bid >> 3) & 7;               // quad 0..7
    if (mt * 256 >= M) return;

    const int tid  = threadIdx.x;
    const int w    = tid >> 6;          // 0..3 (m-wave)
    const int lane = tid & 63;
    const int lr   = lane & 15;
    const int kg   = lane >> 4;         // 0..3 (k-slab)
    const int mbase = mt * 256 + w * 64;

    int tile[4];
    #pragma unroll
    for (int fm = 0; fm < 4; ++fm) {
        int t = (mbase + fm * 16) >> 4;
        tile[fm] = (t < NT) ? t : NT - 1;
    }
    const bf16* Wb = Wg + ((size_t)kg * 512 + q * 64 + lr) * 8;

    f32x4 acc[4][4] = {};   // [fm][gate]

    #pragma unroll
    for (int ch = 0; ch < 12; ++ch) {
        bf16x8 a[4];
        #pragma unroll
        for (int fm = 0; fm < 4; ++fm) {
            const bf16* ap = (ch < 8)
                ? XT + ((size_t)tile[fm] * 32 + ch * 4 + kg) * 128 + lr * 8
                : HT + ((size_t)tile[fm] * 16 + (ch - 8) * 4 + kg) * 128 + lr * 8;
            a[fm] = *reinterpret_cast<const bf16x8*>(ap);
        }
        // chunks <8: gates {0,1,2}; chunks >=8: gates {0,1,3}
        __builtin_amdgcn_s_setprio(1);
        #pragma unroll
        for (int gi = 0; gi < 3; ++gi) {
            const int g = (ch < 8) ? gi : ((gi == 2) ? 3 : gi);
            bf16x8 b = *reinterpret_cast<const bf16x8*>(
                Wb + ((size_t)ch * 4 * 512 + g * 16) * 8);
            #pragma unroll
            for (int fm = 0; fm < 4; ++fm)
                acc[fm][g] = __builtin_amdgcn_mfma_f32_16x16x32_bf16(
                    a[fm], b, acc[fm][g], 0, 0, 0);
        }
        __builtin_amdgcn_s_setprio(0);
    }

    // ---- fused GRU epilogue (gates = the 4 n-frags, lane-local) ----
    const float br  = bg[q * 64 + lr];
    const float bz  = bg[q * 64 + 16 + lr];
    const float bin = bg[q * 64 + 32 + lr];
    const float bhn = bg[q * 64 + 48 + lr];
    const int c = q * 16 + lr;          // hid col 0..127
    #pragma unroll
    for (int fm = 0; fm < 4; ++fm) {
        #pragma unroll
        for (int r = 0; r < 4; ++r) {
            const int row = mbase + fm * 16 + kg * 4 + r;
            if (row >= M) continue;
            float rr = fast_sigmoid(acc[fm][0][r] + br);
            float zz = fast_sigmoid(acc[fm][1][r] + bz);
            float nn = fast_tanh(acc[fm][2][r] + bin +
                                 rr * (acc[fm][3][r] + bhn));
            const size_t hti = ((size_t)(row >> 4) * 16 + (c >> 3)) * 128
                               + (row & 15) * 8 + (c & 7);
            float hin = __bfloat162float(HT[hti]);
            float hv = (1.0f - zz) * nn + zz * hin;
            if (FINAL) {
                h_out[(size_t)row * 128 + c] = hv;
            } else {
                HTout[hti] = __float2bfloat16(hv);
            }
        }
    }
}

// ---------------------------------------------------------------------------
// Fused setup kernel: deg histogram + weight prep + activation tiling.
// ---------------------------------------------------------------------------
#define WSD_N  65536
#define WG_N   196608
#define PREP_N (WSD_N + WG_N + 512)
__global__ __launch_bounds__(256)
void setup_kernel(const int* __restrict__ dst, int* __restrict__ cnt,
                  const float* __restrict__ W_msg,
                  const float* __restrict__ w_ih,
                  const float* __restrict__ w_hh,
                  const float* __restrict__ b_ih,
                  const float* __restrict__ b_hh,
                  bf16* __restrict__ Wsd, bf16* __restrict__ Wg,
                  float* __restrict__ bg,
                  const float* __restrict__ x, const float* __restrict__ h0,
                  bf16* __restrict__ XT, bf16* __restrict__ HT0) {
    int gid = blockIdx.x * 256 + threadIdx.x;
    if (gid < N_EDGES) {
        atomicAdd(&cnt[dst[gid]], 1);
        return;
    }
    gid -= N_EDGES;
    if (gid < PREP_N) {
        if (gid < WSD_N) {
            int kc = gid >> 11;
            int j  = (gid >> 3) & 255;
            int e  = gid & 7;
            int k  = kc * 8 + e;
            float v = (j < 128) ? W_msg[(size_t)j * 512 + k]
                                : W_msg[(size_t)(j - 128) * 512 + 256 + k];
            Wsd[gid] = __float2bfloat16(v);
        } else if (gid < WSD_N + WG_N) {
            int i  = gid - WSD_N;
            int kc = i >> 12;            // 0..47
            int j  = (i >> 3) & 511;
            int e  = i & 7;
            int k  = kc * 8 + e;         // 0..383
            int q = j >> 6, g = (j >> 4) & 3, lr = j & 15;
            int c = q * 16 + lr;
            float v;
            if (k < 256) v = (g < 3) ? w_ih[(size_t)(g * 128 + c) * 256 + k] : 0.0f;
            else         v = (g == 2) ? 0.0f
                           : w_hh[(size_t)(((g == 3) ? 2 : g) * 128 + c) * 128 + (k - 256)];
            Wg[i] = __float2bfloat16(v);
        } else {
            int jp = gid - WSD_N - WG_N;
            int q = jp >> 6, g = (jp >> 4) & 3, lr = jp & 15;
            int c = q * 16 + lr;
            float v;
            if (g == 0)      v = b_ih[c] + b_hh[c];
            else if (g == 1) v = b_ih[128 + c] + b_hh[128 + c];
            else if (g == 2) v = b_ih[256 + c];
            else             v = b_hh[256 + c];
            bg[jp] = v;
        }
        return;
    }
    gid -= PREP_N;
    if (gid >= N_NODES * 32) return;
    const int half = (gid >= N_NODES * 16);
    const int i  = half ? gid - N_NODES * 16 : gid;
    const int v  = i >> 4;
    const int kc = i & 15;
    const float* src = (half ? h0 : x) + (size_t)v * 128 + kc * 8;
    const float4 f0 = *reinterpret_cast<const float4*>(src);
    const float4 f1 = *reinterpret_cast<const float4*>(src + 4);
    bf16 tmp[8];
    tmp[0] = __float2bfloat16(f0.x); tmp[1] = __float2bfloat16(f0.y);
    tmp[2] = __float2bfloat16(f0.z); tmp[3] = __float2bfloat16(f0.w);
    tmp[4] = __float2bfloat16(f1.x); tmp[5] = __float2bfloat16(f1.y);
    tmp[6] = __float2bfloat16(f1.z); tmp[7] = __float2bfloat16(f1.w);
    bf16* dstp = half
        ? HT0 + ((size_t)(v >> 4) * 16 + kc) * 128 + (v & 15) * 8
        : XT  + ((size_t)(v >> 4) * 32 + kc) * 128 + (v & 15) * 8;
    *reinterpret_cast<float4*>(dstp) = *reinterpret_cast<const float4*>(tmp);
}

// ---------------------------------------------------------------------------
// CSR build (graph fixed across rounds)
// ---------------------------------------------------------------------------
__global__ __launch_bounds__(256)
void csr_alloc_kernel(const int* __restrict__ cnt, int* __restrict__ off,
                      int* __restrict__ total, int N) {
    int v = blockIdx.x * 256 + threadIdx.x;
    int lane = threadIdx.x & 63;
    int c = (v < N) ? cnt[v] : 0;
    int s = c;
    #pragma unroll
    for (int d = 1; d < 64; d <<= 1) {
        int t = __shfl_up(s, d, 64);
        if (lane >= d) s += t;
    }
    int wave_total = __shfl(s, 63, 64);
    int base = 0;
    if (lane == 63) base = atomicAdd(total, wave_total);
    base = __shfl(base, 63, 64);
    if (v < N) off[v] = base + s - c;
}

__global__ __launch_bounds__(256)
void fill_csr_kernel(const int* __restrict__ src, const int* __restrict__ dst,
                     const int* __restrict__ off, int* __restrict__ cursor,
                     int* __restrict__ csr, int E) {
    int e = blockIdx.x * 256 + threadIdx.x;
    if (e >= E) return;
    int d = dst[e];
    int pos = atomicAdd(&cursor[d], 1);
    csr[off[d] + pos] = src[e];
}

// ---------------------------------------------------------------------------
// Gather-aggregate: 4 lane-groups x 16 lanes; 4 edges / load instruction;
// R20: unroll 4 (16 edges in flight). 2 shfl_xor reduce; 16B tiled c-write.
// ---------------------------------------------------------------------------
__global__ __launch_bounds__(256)
void agg_kernel(const bf16* __restrict__ SD, const int* __restrict__ csr,
                const int* __restrict__ off, const int* __restrict__ cnt,
                const float* __restrict__ b_msg, bf16* __restrict__ XT, int N) {
    const int v    = (blockIdx.x * 256 + threadIdx.x) >> 6;
    const int lane = threadIdx.x & 63;
    if (v >= N) return;
    const int g    = lane >> 4;     // edge-group 0..3
    const int sl   = lane & 15;     // 8-col slot
    const int deg  = cnt[v];
    const int base = off[v];

    float acc[8] = {};
    #pragma unroll 4
    for (int k = g; k < deg; k += 4) {
        int s0 = csr[base + k];
        bf16x8 row = *reinterpret_cast<const bf16x8*>(
            SD + (size_t)s0 * 256 + sl * 8);
        #pragma unroll
        for (int e = 0; e < 8; ++e) acc[e] += (float)row[e];
    }
    #pragma unroll
    for (int e = 0; e < 8; ++e) {
        acc[e] += __shfl_xor(acc[e], 16, 64);
        acc[e] += __shfl_xor(acc[e], 32, 64);
    }

    if (g != 0) return;
    bf16 outb[8];
    if (deg > 0) {
        const float inv = 1.0f / (float)deg;
        bf16x8 d8 = *reinterpret_cast<const bf16x8*>(
            SD + (size_t)v * 256 + 128 + sl * 8);
        const float4 b0 = *reinterpret_cast<const float4*>(b_msg + sl * 8);
        const float4 b1 = *reinterpret_cast<const float4*>(b_msg + sl * 8 + 4);
        const float bm[8] = {b0.x, b0.y, b0.z, b0.w, b1.x, b1.y, b1.z, b1.w};
        #pragma unroll
        for (int e = 0; e < 8; ++e)
            outb[e] = __float2bfloat16(acc[e] * inv + (float)d8[e] + bm[e]);
    } else {
        #pragma unroll
        for (int e = 0; e < 8; ++e) outb[e] = __float2bfloat16(0.0f);
    }
    bf16* dst = XT + ((size_t)(v >> 4) * 32 + 16 + sl) * 128 + (v & 15) * 8;
    *reinterpret_cast<float4*>(dst) = *reinterpret_cast<const float4*>(outb);
}

// ---------------------------------------------------------------------------
extern "C" void kernel_launch(void* const* d_in, const int* in_sizes, int n_in,
                              void* d_out, int out_size, void* d_ws, size_t ws_size,
                              hipStream_t stream) {
    const float* x     = (const float*)d_in[0];
    const float* h0    = (const float*)d_in[1];
    const float* W_msg = (const float*)d_in[2];
    const float* b_msg = (const float*)d_in[3];
    const float* w_ih  = (const float*)d_in[4];
    const float* w_hh  = (const float*)d_in[5];
    const float* b_ih  = (const float*)d_in[6];
    const float* b_hh  = (const float*)d_in[7];
    const int*   src   = (const int*)d_in[8];
    const int*   dst   = (const int*)d_in[9];
    float* h = (float*)d_out;

    char* ws = (char*)d_ws;
    size_t off_b = 0;
    auto alloc = [&](size_t bytes) -> void* {
        void* p = ws + off_b;
        off_b = (off_b + bytes + 255) & ~(size_t)255;
        return p;
    };
    int*   meta   = (int*)  alloc(((size_t)2 * N_NODES + 64) * 4);
    int*   cnt    = meta;
    int*   cursor = meta + N_NODES;
    int*   total  = meta + 2 * N_NODES;
    int*   off    = (int*)  alloc((size_t)N_NODES * 4);
    int*   csr    = (int*)  alloc((size_t)N_EDGES * 4);
    bf16*  Wsd_b  = (bf16*) alloc((size_t)WSD_N * 2);
    bf16*  Wg_b   = (bf16*) alloc((size_t)WG_N * 2);
    float* bg     = (float*)alloc(512 * 4);
    bf16*  XT     = (bf16*) alloc((size_t)NT * 32 * 128 * 2);   // 25.6MB
    bf16*  HT0    = (bf16*) alloc((size_t)NT * 16 * 128 * 2);   // 12.8MB
    bf16*  HT1    = (bf16*) alloc((size_t)NT * 16 * 128 * 2);   // 12.8MB
    bf16*  SD     = (bf16*) alloc((size_t)N_NODES * 256 * 2);

    // --- setup: memset -> fused(deg|prep|conv) -> csr alloc -> csr fill ---
    hipMemsetAsync(meta, 0, ((size_t)2 * N_NODES + 64) * 4, stream);
    const int SETUP_N = N_EDGES + PREP_N + N_NODES * 32;
    setup_kernel<<<(SETUP_N + 255) / 256, 256, 0, stream>>>(
        dst, cnt, W_msg, w_ih, w_hh, b_ih, b_hh, Wsd_b, Wg_b, bg,
        x, h0, XT, HT0);
    csr_alloc_kernel<<<(N_NODES + 255) / 256, 256, 0, stream>>>(cnt, off, total, N_NODES);
    fill_csr_kernel<<<(N_EDGES + 255) / 256, 256, 0, stream>>>(src, dst, off, cursor,
                                                               csr, N_EDGES);

    // XCD-aware 1D grids: 25 groups of (8 m-tiles x quads)
    const int SD_GRID    = 25 * 32;   // 800  (mt 0..199, bn 0..3)
    const int GATES_GRID = 25 * 64;   // 1600 (mt 0..199, q 0..7)
    const int AGG_GRID   = (N_NODES * 64 + 255) / 256;

    // ---- round 0: h = HT0 -> HT1 ----
    gemm_sd_kernel<<<SD_GRID, 256, 0, stream>>>(XT, HT0, Wsd_b, SD, N_NODES);
    agg_kernel<<<AGG_GRID, 256, 0, stream>>>(
        SD, csr, off, cnt, b_msg, XT, N_NODES);
    gates_kernel<0><<<GATES_GRID, 256, 0, stream>>>(
        XT, HT0, Wg_b, bg, nullptr, HT1, N_NODES);

    // ---- round 1 (final): h = HT1 -> d_out ----
    gemm_sd_kernel<<<SD_GRID, 256, 0, stream>>>(XT, HT1, Wsd_b, SD, N_NODES);
    agg_kernel<<<AGG_GRID, 256, 0, stream>>>(
        SD, csr, off, cnt, b_msg, XT, N_NODES);
    gates_kernel<1><<<GATES_GRID, 256, 0, stream>>>(
        XT, HT1, Wg_b, bg, h, nullptr, N_NODES);
}

// Round 21
// 219.492 us; speedup vs baseline: 1.4610x; 1.4610x over previous
//
#include <hip/hip_runtime.h>
#include <hip/hip_bf16.h>

typedef __hip_bfloat16 bf16;
typedef __bf16 bf16x8 __attribute__((ext_vector_type(8)));
typedef float  f32x4  __attribute__((ext_vector_type(4)));

#define N_NODES 50000
#define N_EDGES 400000
#define NT 3125    // N_NODES/16 row-tiles
#define HID 128
#define MSG 128

// Activation layouts (MFMA-fragment-tiled):
//   XT[t][kc 0..31][r 0..15][e 0..8)  -- x at kc 0..15, c at kc 16..31
//   HT[t][kc 0..15][r][e]             -- h (bf16, ping-pong HT0/HT1)
// Weights: Wsd_f[kc 0..31][j 0..255][8] and Wg[kc 0..47][j' 0..511][8],
// both LINEAR fragment layout -> B-frags read DIRECT from global (L2-hot).

// ---------------------------------------------------------------------------
// SD GEMM: SD[M,256] = [x|h] @ Wsd^T. BM=256, BN=64, 4 waves.
// Direct-global B frags; single barrier (epilogue C-tile). XCD grid (800).
// ---------------------------------------------------------------------------
__global__ __launch_bounds__(256, 4)
void gemm_sd_kernel(const bf16* __restrict__ XT,
                    const bf16* __restrict__ HT,
                    const bf16* __restrict__ W,      // [32][256][8] linear frag
                    bf16* __restrict__ O, int M) {
    constexpr int K = 256, J = 256;
    __shared__ __align__(16) bf16 Cs[256 * 64];      // 32KB C tile

    const int bid = blockIdx.x;
    const int mt  = (bid >> 5) * 8 + (bid & 7);      // m-tile 0..199
    const int bnt = (bid >> 3) & 3;
    if (mt * 256 >= M) return;                       // uniform
    const int bm = mt * 256;
    const int bn = bnt * 64;
    const int tid = threadIdx.x;

    const int w    = tid >> 6;
    const int lane = tid & 63;
    const int lr   = lane & 15;
    const int kg   = lane >> 4;
    const int mbase = bm + w * 64;

    int tile[4];
    #pragma unroll
    for (int fm = 0; fm < 4; ++fm) {
        int t = (mbase + fm * 16) >> 4;
        tile[fm] = (t < NT) ? t : NT - 1;            // OOB discarded at store
    }
    const bf16* Wb = W + ((size_t)kg * 256 + bn + lr) * 8;

    f32x4 acc[4][4] = {};

    #pragma unroll
    for (int k0 = 0; k0 < K; k0 += 32) {
        bf16x8 a[4];
        #pragma unroll
        for (int fm = 0; fm < 4; ++fm) {
            const bf16* ap = (k0 < 128)
                ? XT + ((size_t)tile[fm] * 32 + (k0 >> 3) + kg) * 128 + lr * 8
                : HT + ((size_t)tile[fm] * 16 + ((k0 - 128) >> 3) + kg) * 128 + lr * 8;
            a[fm] = *reinterpret_cast<const bf16x8*>(ap);
        }
        __builtin_amdgcn_s_setprio(1);
        #pragma unroll
        for (int fn = 0; fn < 4; ++fn) {
            bf16x8 b = *reinterpret_cast<const bf16x8*>(
                Wb + (((size_t)(k0 >> 3)) * 256 + fn * 16) * 8);
            #pragma unroll
            for (int fm = 0; fm < 4; ++fm)
                acc[fm][fn] = __builtin_amdgcn_mfma_f32_16x16x32_bf16(
                    a[fm], b, acc[fm][fn], 0, 0, 0);
        }
        __builtin_amdgcn_s_setprio(0);
    }

    // epilogue: C tile through LDS (swizzled) for coalesced 128B stores
    #pragma unroll
    for (int fn = 0; fn < 4; ++fn) {
        int col = fn * 16 + lr;
        #pragma unroll
        for (int fm = 0; fm < 4; ++fm) {
            int rbase = w * 64 + fm * 16 + kg * 4;
            #pragma unroll
            for (int r = 0; r < 4; ++r) {
                int row = rbase + r;
                int cs = ((((col >> 3) ^ ((row >> 2) & 7))) << 3) | (col & 7);
                Cs[row * 64 + cs] = __float2bfloat16(acc[fm][fn][r]);
            }
        }
    }
    __syncthreads();
    const int colblk = tid & 7;
    const int rbase_o = tid >> 3;
    #pragma unroll
    for (int it = 0; it < 8; ++it) {
        int row = it * 32 + rbase_o;
        int grow = bm + row;
        if (grow < M) {
            int g = (row >> 2) & 7;
            const float4 v = *reinterpret_cast<const float4*>(
                &Cs[row * 64 + ((colblk ^ g) << 3)]);
            *reinterpret_cast<float4*>(O + (size_t)grow * J + bn + colblk * 8) = v;
        }
    }
}

// ---------------------------------------------------------------------------
// Fused gates GEMM + GRU: barrier-free / LDS-free, XCD grid, chunk-skip,
// fragment-tiled A, bf16 hin, setprio. __launch_bounds__(256,4) -- R20's
// (256,6) forced VGPR 64->40 and spilled acc (154MB scratch, 1.5x slower).
// Rule: min-waves bound must keep implied VGPR cap >= live state at the
// NEXT HW granule; check -Rpass-analysis before benching.
// ---------------------------------------------------------------------------
__device__ __forceinline__ float fast_sigmoid(float x) {
    return 1.0f / (1.0f + __expf(-x));
}
__device__ __forceinline__ float fast_tanh(float x) {
    float e = __expf(-2.0f * fabsf(x));
    float t = (1.0f - e) / (1.0f + e);
    return copysignf(t, x);
}

template <int FINAL>
__global__ __launch_bounds__(256, 4)
void gates_kernel(const bf16* __restrict__ XT,
                  const bf16* __restrict__ HT,     // tiled h (read)
                  const bf16* __restrict__ Wg,     // [48][512][8] linear
                  const float* __restrict__ bg,    // [512] fused bias
                  float* __restrict__ h_out,       // f32 out (FINAL)
                  bf16* __restrict__ HTout,        // tiled h out (non-final)
                  int M) {
    const int bid = blockIdx.x;
    const int mt  = (bid >> 6) * 8 + (bid & 7);   // m-tile 0..199
    const int q   = (bid >> 3) & 7;               // quad 0..7
    if (mt * 256 >= M) return;

    const int tid  = threadIdx.x;
    const int w    = tid >> 6;          // 0..3 (m-wave)
    const int lane = tid & 63;
    const int lr   = lane & 15;
    const int kg   = lane >> 4;         // 0..3 (k-slab)
    const int mbase = mt * 256 + w * 64;

    int tile[4];
    #pragma unroll
    for (int fm = 0; fm < 4; ++fm) {
        int t = (mbase + fm * 16) >> 4;
        tile[fm] = (t < NT) ? t : NT - 1;
    }
    const bf16* Wb = Wg + ((size_t)kg * 512 + q * 64 + lr) * 8;

    f32x4 acc[4][4] = {};   // [fm][gate]

    #pragma unroll
    for (int ch = 0; ch < 12; ++ch) {
        bf16x8 a[4];
        #pragma unroll
        for (int fm = 0; fm < 4; ++fm) {
            const bf16* ap = (ch < 8)
                ? XT + ((size_t)tile[fm] * 32 + ch * 4 + kg) * 128 + lr * 8
                : HT + ((size_t)tile[fm] * 16 + (ch - 8) * 4 + kg) * 128 + lr * 8;
            a[fm] = *reinterpret_cast<const bf16x8*>(ap);
        }
        // chunks <8: gates {0,1,2}; chunks >=8: gates {0,1,3}
        __builtin_amdgcn_s_setprio(1);
        #pragma unroll
        for (int gi = 0; gi < 3; ++gi) {
            const int g = (ch < 8) ? gi : ((gi == 2) ? 3 : gi);
            bf16x8 b = *reinterpret_cast<const bf16x8*>(
                Wb + ((size_t)ch * 4 * 512 + g * 16) * 8);
            #pragma unroll
            for (int fm = 0; fm < 4; ++fm)
                acc[fm][g] = __builtin_amdgcn_mfma_f32_16x16x32_bf16(
                    a[fm], b, acc[fm][g], 0, 0, 0);
        }
        __builtin_amdgcn_s_setprio(0);
    }

    // ---- fused GRU epilogue (gates = the 4 n-frags, lane-local) ----
    const float br  = bg[q * 64 + lr];
    const float bz  = bg[q * 64 + 16 + lr];
    const float bin = bg[q * 64 + 32 + lr];
    const float bhn = bg[q * 64 + 48 + lr];
    const int c = q * 16 + lr;          // hid col 0..127
    #pragma unroll
    for (int fm = 0; fm < 4; ++fm) {
        #pragma unroll
        for (int r = 0; r < 4; ++r) {
            const int row = mbase + fm * 16 + kg * 4 + r;
            if (row >= M) continue;
            float rr = fast_sigmoid(acc[fm][0][r] + br);
            float zz = fast_sigmoid(acc[fm][1][r] + bz);
            float nn = fast_tanh(acc[fm][2][r] + bin +
                                 rr * (acc[fm][3][r] + bhn));
            const size_t hti = ((size_t)(row >> 4) * 16 + (c >> 3)) * 128
                               + (row & 15) * 8 + (c & 7);
            float hin = __bfloat162float(HT[hti]);
            float hv = (1.0f - zz) * nn + zz * hin;
            if (FINAL) {
                h_out[(size_t)row * 128 + c] = hv;
            } else {
                HTout[hti] = __float2bfloat16(hv);
            }
        }
    }
}

// ---------------------------------------------------------------------------
// Fused setup kernel: deg histogram + weight prep + activation tiling.
// ---------------------------------------------------------------------------
#define WSD_N  65536
#define WG_N   196608
#define PREP_N (WSD_N + WG_N + 512)
__global__ __launch_bounds__(256)
void setup_kernel(const int* __restrict__ dst, int* __restrict__ cnt,
                  const float* __restrict__ W_msg,
                  const float* __restrict__ w_ih,
                  const float* __restrict__ w_hh,
                  const float* __restrict__ b_ih,
                  const float* __restrict__ b_hh,
                  bf16* __restrict__ Wsd, bf16* __restrict__ Wg,
                  float* __restrict__ bg,
                  const float* __restrict__ x, const float* __restrict__ h0,
                  bf16* __restrict__ XT, bf16* __restrict__ HT0) {
    int gid = blockIdx.x * 256 + threadIdx.x;
    if (gid < N_EDGES) {
        atomicAdd(&cnt[dst[gid]], 1);
        return;
    }
    gid -= N_EDGES;
    if (gid < PREP_N) {
        if (gid < WSD_N) {
            int kc = gid >> 11;
            int j  = (gid >> 3) & 255;
            int e  = gid & 7;
            int k  = kc * 8 + e;
            float v = (j < 128) ? W_msg[(size_t)j * 512 + k]
                                : W_msg[(size_t)(j - 128) * 512 + 256 + k];
            Wsd[gid] = __float2bfloat16(v);
        } else if (gid < WSD_N + WG_N) {
            int i  = gid - WSD_N;
            int kc = i >> 12;            // 0..47
            int j  = (i >> 3) & 511;
            int e  = i & 7;
            int k  = kc * 8 + e;         // 0..383
            int q = j >> 6, g = (j >> 4) & 3, lr = j & 15;
            int c = q * 16 + lr;
            float v;
            if (k < 256) v = (g < 3) ? w_ih[(size_t)(g * 128 + c) * 256 + k] : 0.0f;
            else         v = (g == 2) ? 0.0f
                           : w_hh[(size_t)(((g == 3) ? 2 : g) * 128 + c) * 128 + (k - 256)];
            Wg[i] = __float2bfloat16(v);
        } else {
            int jp = gid - WSD_N - WG_N;
            int q = jp >> 6, g = (jp >> 4) & 3, lr = jp & 15;
            int c = q * 16 + lr;
            float v;
            if (g == 0)      v = b_ih[c] + b_hh[c];
            else if (g == 1) v = b_ih[128 + c] + b_hh[128 + c];
            else if (g == 2) v = b_ih[256 + c];
            else             v = b_hh[256 + c];
            bg[jp] = v;
        }
        return;
    }
    gid -= PREP_N;
    if (gid >= N_NODES * 32) return;
    const int half = (gid >= N_NODES * 16);
    const int i  = half ? gid - N_NODES * 16 : gid;
    const int v  = i >> 4;
    const int kc = i & 15;
    const float* src = (half ? h0 : x) + (size_t)v * 128 + kc * 8;
    const float4 f0 = *reinterpret_cast<const float4*>(src);
    const float4 f1 = *reinterpret_cast<const float4*>(src + 4);
    bf16 tmp[8];
    tmp[0] = __float2bfloat16(f0.x); tmp[1] = __float2bfloat16(f0.y);
    tmp[2] = __float2bfloat16(f0.z); tmp[3] = __float2bfloat16(f0.w);
    tmp[4] = __float2bfloat16(f1.x); tmp[5] = __float2bfloat16(f1.y);
    tmp[6] = __float2bfloat16(f1.z); tmp[7] = __float2bfloat16(f1.w);
    bf16* dstp = half
        ? HT0 + ((size_t)(v >> 4) * 16 + kc) * 128 + (v & 15) * 8
        : XT  + ((size_t)(v >> 4) * 32 + kc) * 128 + (v & 15) * 8;
    *reinterpret_cast<float4*>(dstp) = *reinterpret_cast<const float4*>(tmp);
}

// ---------------------------------------------------------------------------
// CSR build (graph fixed across rounds)
// ---------------------------------------------------------------------------
__global__ __launch_bounds__(256)
void csr_alloc_kernel(const int* __restrict__ cnt, int* __restrict__ off,
                      int* __restrict__ total, int N) {
    int v = blockIdx.x * 256 + threadIdx.x;
    int lane = threadIdx.x & 63;
    int c = (v < N) ? cnt[v] : 0;
    int s = c;
    #pragma unroll
    for (int d = 1; d < 64; d <<= 1) {
        int t = __shfl_up(s, d, 64);
        if (lane >= d) s += t;
    }
    int wave_total = __shfl(s, 63, 64);
    int base = 0;
    if (lane == 63) base = atomicAdd(total, wave_total);
    base = __shfl(base, 63, 64);
    if (v < N) off[v] = base + s - c;
}

__global__ __launch_bounds__(256)
void fill_csr_kernel(const int* __restrict__ src, const int* __restrict__ dst,
                     const int* __restrict__ off, int* __restrict__ cursor,
                     int* __restrict__ csr, int E) {
    int e = blockIdx.x * 256 + threadIdx.x;
    if (e >= E) return;
    int d = dst[e];
    int pos = atomicAdd(&cursor[d], 1);
    csr[off[d] + pos] = src[e];
}

// ---------------------------------------------------------------------------
// Gather-aggregate: 4 lane-groups x 16 lanes; 4 edges / load instruction;
// unroll 4 (16 edges in flight). 2 shfl_xor reduce; 16B tiled c-write.
// ---------------------------------------------------------------------------
__global__ __launch_bounds__(256)
void agg_kernel(const bf16* __restrict__ SD, const int* __restrict__ csr,
                const int* __restrict__ off, const int* __restrict__ cnt,
                const float* __restrict__ b_msg, bf16* __restrict__ XT, int N) {
    const int v    = (blockIdx.x * 256 + threadIdx.x) >> 6;
    const int lane = threadIdx.x & 63;
    if (v >= N) return;
    const int g    = lane >> 4;     // edge-group 0..3
    const int sl   = lane & 15;     // 8-col slot
    const int deg  = cnt[v];
    const int base = off[v];

    float acc[8] = {};
    #pragma unroll 4
    for (int k = g; k < deg; k += 4) {
        int s0 = csr[base + k];
        bf16x8 row = *reinterpret_cast<const bf16x8*>(
            SD + (size_t)s0 * 256 + sl * 8);
        #pragma unroll
        for (int e = 0; e < 8; ++e) acc[e] += (float)row[e];
    }
    #pragma unroll
    for (int e = 0; e < 8; ++e) {
        acc[e] += __shfl_xor(acc[e], 16, 64);
        acc[e] += __shfl_xor(acc[e], 32, 64);
    }

    if (g != 0) return;
    bf16 outb[8];
    if (deg > 0) {
        const float inv = 1.0f / (float)deg;
        bf16x8 d8 = *reinterpret_cast<const bf16x8*>(
            SD + (size_t)v * 256 + 128 + sl * 8);
        const float4 b0 = *reinterpret_cast<const float4*>(b_msg + sl * 8);
        const float4 b1 = *reinterpret_cast<const float4*>(b_msg + sl * 8 + 4);
        const float bm[8] = {b0.x, b0.y, b0.z, b0.w, b1.x, b1.y, b1.z, b1.w};
        #pragma unroll
        for (int e = 0; e < 8; ++e)
            outb[e] = __float2bfloat16(acc[e] * inv + (float)d8[e] + bm[e]);
    } else {
        #pragma unroll
        for (int e = 0; e < 8; ++e) outb[e] = __float2bfloat16(0.0f);
    }
    bf16* dst = XT + ((size_t)(v >> 4) * 32 + 16 + sl) * 128 + (v & 15) * 8;
    *reinterpret_cast<float4*>(dst) = *reinterpret_cast<const float4*>(outb);
}

// ---------------------------------------------------------------------------
extern "C" void kernel_launch(void* const* d_in, const int* in_sizes, int n_in,
                              void* d_out, int out_size, void* d_ws, size_t ws_size,
                              hipStream_t stream) {
    const float* x     = (const float*)d_in[0];
    const float* h0    = (const float*)d_in[1];
    const float* W_msg = (const float*)d_in[2];
    const float* b_msg = (const float*)d_in[3];
    const float* w_ih  = (const float*)d_in[4];
    const float* w_hh  = (const float*)d_in[5];
    const float* b_ih  = (const float*)d_in[6];
    const float* b_hh  = (const float*)d_in[7];
    const int*   src   = (const int*)d_in[8];
    const int*   dst   = (const int*)d_in[9];
    float* h = (float*)d_out;

    char* ws = (char*)d_ws;
    size_t off_b = 0;
    auto alloc = [&](size_t bytes) -> void* {
        void* p = ws + off_b;
        off_b = (off_b + bytes + 255) & ~(size_t)255;
        return p;
    };
    int*   meta   = (int*)  alloc(((size_t)2 * N_NODES + 64) * 4);
    int*   cnt    = meta;
    int*   cursor = meta + N_NODES;
    int*   total  = meta + 2 * N_NODES;
    int*   off    = (int*)  alloc((size_t)N_NODES * 4);
    int*   csr    = (int*)  alloc((size_t)N_EDGES * 4);
    bf16*  Wsd_b  = (bf16*) alloc((size_t)WSD_N * 2);
    bf16*  Wg_b   = (bf16*) alloc((size_t)WG_N * 2);
    float* bg     = (float*)alloc(512 * 4);
    bf16*  XT     = (bf16*) alloc((size_t)NT * 32 * 128 * 2);   // 25.6MB
    bf16*  HT0    = (bf16*) alloc((size_t)NT * 16 * 128 * 2);   // 12.8MB
    bf16*  HT1    = (bf16*) alloc((size_t)NT * 16 * 128 * 2);   // 12.8MB
    bf16*  SD     = (bf16*) alloc((size_t)N_NODES * 256 * 2);

    // --- setup: memset -> fused(deg|prep|conv) -> csr alloc -> csr fill ---
    hipMemsetAsync(meta, 0, ((size_t)2 * N_NODES + 64) * 4, stream);
    const int SETUP_N = N_EDGES + PREP_N + N_NODES * 32;
    setup_kernel<<<(SETUP_N + 255) / 256, 256, 0, stream>>>(
        dst, cnt, W_msg, w_ih, w_hh, b_ih, b_hh, Wsd_b, Wg_b, bg,
        x, h0, XT, HT0);
    csr_alloc_kernel<<<(N_NODES + 255) / 256, 256, 0, stream>>>(cnt, off, total, N_NODES);
    fill_csr_kernel<<<(N_EDGES + 255) / 256, 256, 0, stream>>>(src, dst, off, cursor,
                                                               csr, N_EDGES);

    // XCD-aware 1D grids: 25 groups of (8 m-tiles x quads)
    const int SD_GRID    = 25 * 32;   // 800  (mt 0..199, bn 0..3)
    const int GATES_GRID = 25 * 64;   // 1600 (mt 0..199, q 0..7)
    const int AGG_GRID   = (N_NODES * 64 + 255) / 256;

    // ---- round 0: h = HT0 -> HT1 ----
    gemm_sd_kernel<<<SD_GRID, 256, 0, stream>>>(XT, HT0, Wsd_b, SD, N_NODES);
    agg_kernel<<<AGG_GRID, 256, 0, stream>>>(
        SD, csr, off, cnt, b_msg, XT, N_NODES);
    gates_kernel<0><<<GATES_GRID, 256, 0, stream>>>(
        XT, HT0, Wg_b, bg, nullptr, HT1, N_NODES);

    // ---- round 1 (final): h = HT1 -> d_out ----
    gemm_sd_kernel<<<SD_GRID, 256, 0, stream>>>(XT, HT1, Wsd_b, SD, N_NODES);
    agg_kernel<<<AGG_GRID, 256, 0, stream>>>(
        SD, csr, off, cnt, b_msg, XT, N_NODES);
    gates_kernel<1><<<GATES_GRID, 256, 0, stream>>>(
        XT, HT1, Wg_b, bg, h, nullptr, N_NODES);
}

// Round 22
// 215.153 us; speedup vs baseline: 1.4905x; 1.0202x over previous
//
#include <hip/hip_runtime.h>
#include <hip/hip_bf16.h>

typedef __hip_bfloat16 bf16;
typedef __bf16 bf16x8 __attribute__((ext_vector_type(8)));
typedef float  f32x4  __attribute__((ext_vector_type(4)));

#define N_NODES 50000
#define N_EDGES 400000
#define NT 3125    // N_NODES/16 row-tiles
#define HID 128
#define MSG 128

// Activation layouts (MFMA-fragment-tiled):
//   XT[t][kc 0..31][r 0..15][e 0..8)  -- x at kc 0..15, c at kc 16..31
//   HT[t][kc 0..15][r][e]             -- h (bf16, ping-pong HT0/HT1)
// Weights: Wsd_f[kc 0..31][j 0..255][8] and Wg[kc 0..47][j' 0..511][8],
// both LINEAR fragment layout -> B-frags read DIRECT from global (L2-hot).

// ---------------------------------------------------------------------------
// SD GEMM: SD[M,256] = [x|h] @ Wsd^T. BM=256, BN=64, 4 waves.
// Direct-global B frags; single barrier (epilogue C-tile). XCD grid (800).
// ---------------------------------------------------------------------------
__global__ __launch_bounds__(256, 4)
void gemm_sd_kernel(const bf16* __restrict__ XT,
                    const bf16* __restrict__ HT,
                    const bf16* __restrict__ W,      // [32][256][8] linear frag
                    bf16* __restrict__ O, int M) {
    constexpr int K = 256, J = 256;
    __shared__ __align__(16) bf16 Cs[256 * 64];      // 32KB C tile

    const int bid = blockIdx.x;
    const int mt  = (bid >> 5) * 8 + (bid & 7);      // m-tile 0..199
    const int bnt = (bid >> 3) & 3;
    if (mt * 256 >= M) return;                       // uniform
    const int bm = mt * 256;
    const int bn = bnt * 64;
    const int tid = threadIdx.x;

    const int w    = tid >> 6;
    const int lane = tid & 63;
    const int lr   = lane & 15;
    const int kg   = lane >> 4;
    const int mbase = bm + w * 64;

    int tile[4];
    #pragma unroll
    for (int fm = 0; fm < 4; ++fm) {
        int t = (mbase + fm * 16) >> 4;
        tile[fm] = (t < NT) ? t : NT - 1;            // OOB discarded at store
    }
    const bf16* Wb = W + ((size_t)kg * 256 + bn + lr) * 8;

    f32x4 acc[4][4] = {};

    #pragma unroll
    for (int k0 = 0; k0 < K; k0 += 32) {
        bf16x8 a[4];
        #pragma unroll
        for (int fm = 0; fm < 4; ++fm) {
            const bf16* ap = (k0 < 128)
                ? XT + ((size_t)tile[fm] * 32 + (k0 >> 3) + kg) * 128 + lr * 8
                : HT + ((size_t)tile[fm] * 16 + ((k0 - 128) >> 3) + kg) * 128 + lr * 8;
            a[fm] = *reinterpret_cast<const bf16x8*>(ap);
        }
        __builtin_amdgcn_s_setprio(1);
        #pragma unroll
        for (int fn = 0; fn < 4; ++fn) {
            bf16x8 b = *reinterpret_cast<const bf16x8*>(
                Wb + (((size_t)(k0 >> 3)) * 256 + fn * 16) * 8);
            #pragma unroll
            for (int fm = 0; fm < 4; ++fm)
                acc[fm][fn] = __builtin_amdgcn_mfma_f32_16x16x32_bf16(
                    a[fm], b, acc[fm][fn], 0, 0, 0);
        }
        __builtin_amdgcn_s_setprio(0);
    }

    // epilogue: C tile through LDS (swizzled) for coalesced 128B stores
    #pragma unroll
    for (int fn = 0; fn < 4; ++fn) {
        int col = fn * 16 + lr;
        #pragma unroll
        for (int fm = 0; fm < 4; ++fm) {
            int rbase = w * 64 + fm * 16 + kg * 4;
            #pragma unroll
            for (int r = 0; r < 4; ++r) {
                int row = rbase + r;
                int cs = ((((col >> 3) ^ ((row >> 2) & 7))) << 3) | (col & 7);
                Cs[row * 64 + cs] = __float2bfloat16(acc[fm][fn][r]);
            }
        }
    }
    __syncthreads();
    const int colblk = tid & 7;
    const int rbase_o = tid >> 3;
    #pragma unroll
    for (int it = 0; it < 8; ++it) {
        int row = it * 32 + rbase_o;
        int grow = bm + row;
        if (grow < M) {
            int g = (row >> 2) & 7;
            const float4 v = *reinterpret_cast<const float4*>(
                &Cs[row * 64 + ((colblk ^ g) << 3)]);
            *reinterpret_cast<float4*>(O + (size_t)grow * J + bn + colblk * 8) = v;
        }
    }
}

// ---------------------------------------------------------------------------
// Fused gates GEMM + GRU: barrier-free / LDS-free, XCD grid, chunk-skip,
// fragment-tiled A, bf16 hin, setprio, __launch_bounds__(256,4) (proven;
// (256,6) and (256,8) both spilled the 64-VGPR accumulator).
// ---------------------------------------------------------------------------
__device__ __forceinline__ float fast_sigmoid(float x) {
    return 1.0f / (1.0f + __expf(-x));
}
__device__ __forceinline__ float fast_tanh(float x) {
    float e = __expf(-2.0f * fabsf(x));
    float t = (1.0f - e) / (1.0f + e);
    return copysignf(t, x);
}

template <int FINAL>
__global__ __launch_bounds__(256, 4)
void gates_kernel(const bf16* __restrict__ XT,
                  const bf16* __restrict__ HT,     // tiled h (read)
                  const bf16* __restrict__ Wg,     // [48][512][8] linear
                  const float* __restrict__ bg,    // [512] fused bias
                  float* __restrict__ h_out,       // f32 out (FINAL)
                  bf16* __restrict__ HTout,        // tiled h out (non-final)
                  int M) {
    const int bid = blockIdx.x;
    const int mt  = (bid >> 6) * 8 + (bid & 7);   // m-tile 0..199
    const int q   = (bid >> 3) & 7;               // quad 0..7
    if (mt * 256 >= M) return;

    const int tid  = threadIdx.x;
    const int w    = tid >> 6;          // 0..3 (m-wave)
    const int lane = tid & 63;
    const int lr   = lane & 15;
    const int kg   = lane >> 4;         // 0..3 (k-slab)
    const int mbase = mt * 256 + w * 64;

    int tile[4];
    #pragma unroll
    for (int fm = 0; fm < 4; ++fm) {
        int t = (mbase + fm * 16) >> 4;
        tile[fm] = (t < NT) ? t : NT - 1;
    }
    const bf16* Wb = Wg + ((size_t)kg * 512 + q * 64 + lr) * 8;

    f32x4 acc[4][4] = {};   // [fm][gate]

    #pragma unroll
    for (int ch = 0; ch < 12; ++ch) {
        bf16x8 a[4];
        #pragma unroll
        for (int fm = 0; fm < 4; ++fm) {
            const bf16* ap = (ch < 8)
                ? XT + ((size_t)tile[fm] * 32 + ch * 4 + kg) * 128 + lr * 8
                : HT + ((size_t)tile[fm] * 16 + (ch - 8) * 4 + kg) * 128 + lr * 8;
            a[fm] = *reinterpret_cast<const bf16x8*>(ap);
        }
        // chunks <8: gates {0,1,2}; chunks >=8: gates {0,1,3}
        __builtin_amdgcn_s_setprio(1);
        #pragma unroll
        for (int gi = 0; gi < 3; ++gi) {
            const int g = (ch < 8) ? gi : ((gi == 2) ? 3 : gi);
            bf16x8 b = *reinterpret_cast<const bf16x8*>(
                Wb + ((size_t)ch * 4 * 512 + g * 16) * 8);
            #pragma unroll
            for (int fm = 0; fm < 4; ++fm)
                acc[fm][g] = __builtin_amdgcn_mfma_f32_16x16x32_bf16(
                    a[fm], b, acc[fm][g], 0, 0, 0);
        }
        __builtin_amdgcn_s_setprio(0);
    }

    // ---- fused GRU epilogue (gates = the 4 n-frags, lane-local) ----
    const float br  = bg[q * 64 + lr];
    const float bz  = bg[q * 64 + 16 + lr];
    const float bin = bg[q * 64 + 32 + lr];
    const float bhn = bg[q * 64 + 48 + lr];
    const int c = q * 16 + lr;          // hid col 0..127
    #pragma unroll
    for (int fm = 0; fm < 4; ++fm) {
        #pragma unroll
        for (int r = 0; r < 4; ++r) {
            const int row = mbase + fm * 16 + kg * 4 + r;
            if (row >= M) continue;
            float rr = fast_sigmoid(acc[fm][0][r] + br);
            float zz = fast_sigmoid(acc[fm][1][r] + bz);
            float nn = fast_tanh(acc[fm][2][r] + bin +
                                 rr * (acc[fm][3][r] + bhn));
            const size_t hti = ((size_t)(row >> 4) * 16 + (c >> 3)) * 128
                               + (row & 15) * 8 + (c & 7);
            float hin = __bfloat162float(HT[hti]);
            float hv = (1.0f - zz) * nn + zz * hin;
            if (FINAL) {
                h_out[(size_t)row * 128 + c] = hv;
            } else {
                HTout[hti] = __float2bfloat16(hv);
            }
        }
    }
}

// ---------------------------------------------------------------------------
// Fused setup kernel: deg histogram + weight prep + activation tiling.
// ---------------------------------------------------------------------------
#define WSD_N  65536
#define WG_N   196608
#define PREP_N (WSD_N + WG_N + 512)
__global__ __launch_bounds__(256)
void setup_kernel(const int* __restrict__ dst, int* __restrict__ cnt,
                  const float* __restrict__ W_msg,
                  const float* __restrict__ w_ih,
                  const float* __restrict__ w_hh,
                  const float* __restrict__ b_ih,
                  const float* __restrict__ b_hh,
                  bf16* __restrict__ Wsd, bf16* __restrict__ Wg,
                  float* __restrict__ bg,
                  const float* __restrict__ x, const float* __restrict__ h0,
                  bf16* __restrict__ XT, bf16* __restrict__ HT0) {
    int gid = blockIdx.x * 256 + threadIdx.x;
    if (gid < N_EDGES) {
        atomicAdd(&cnt[dst[gid]], 1);
        return;
    }
    gid -= N_EDGES;
    if (gid < PREP_N) {
        if (gid < WSD_N) {
            int kc = gid >> 11;
            int j  = (gid >> 3) & 255;
            int e  = gid & 7;
            int k  = kc * 8 + e;
            float v = (j < 128) ? W_msg[(size_t)j * 512 + k]
                                : W_msg[(size_t)(j - 128) * 512 + 256 + k];
            Wsd[gid] = __float2bfloat16(v);
        } else if (gid < WSD_N + WG_N) {
            int i  = gid - WSD_N;
            int kc = i >> 12;            // 0..47
            int j  = (i >> 3) & 511;
            int e  = i & 7;
            int k  = kc * 8 + e;         // 0..383
            int q = j >> 6, g = (j >> 4) & 3, lr = j & 15;
            int c = q * 16 + lr;
            float v;
            if (k < 256) v = (g < 3) ? w_ih[(size_t)(g * 128 + c) * 256 + k] : 0.0f;
            else         v = (g == 2) ? 0.0f
                           : w_hh[(size_t)(((g == 3) ? 2 : g) * 128 + c) * 128 + (k - 256)];
            Wg[i] = __float2bfloat16(v);
        } else {
            int jp = gid - WSD_N - WG_N;
            int q = jp >> 6, g = (jp >> 4) & 3, lr = jp & 15;
            int c = q * 16 + lr;
            float v;
            if (g == 0)      v = b_ih[c] + b_hh[c];
            else if (g == 1) v = b_ih[128 + c] + b_hh[128 + c];
            else if (g == 2) v = b_ih[256 + c];
            else             v = b_hh[256 + c];
            bg[jp] = v;
        }
        return;
    }
    gid -= PREP_N;
    if (gid >= N_NODES * 32) return;
    const int half = (gid >= N_NODES * 16);
    const int i  = half ? gid - N_NODES * 16 : gid;
    const int v  = i >> 4;
    const int kc = i & 15;
    const float* src = (half ? h0 : x) + (size_t)v * 128 + kc * 8;
    const float4 f0 = *reinterpret_cast<const float4*>(src);
    const float4 f1 = *reinterpret_cast<const float4*>(src + 4);
    bf16 tmp[8];
    tmp[0] = __float2bfloat16(f0.x); tmp[1] = __float2bfloat16(f0.y);
    tmp[2] = __float2bfloat16(f0.z); tmp[3] = __float2bfloat16(f0.w);
    tmp[4] = __float2bfloat16(f1.x); tmp[5] = __float2bfloat16(f1.y);
    tmp[6] = __float2bfloat16(f1.z); tmp[7] = __float2bfloat16(f1.w);
    bf16* dstp = half
        ? HT0 + ((size_t)(v >> 4) * 16 + kc) * 128 + (v & 15) * 8
        : XT  + ((size_t)(v >> 4) * 32 + kc) * 128 + (v & 15) * 8;
    *reinterpret_cast<float4*>(dstp) = *reinterpret_cast<const float4*>(tmp);
}

// ---------------------------------------------------------------------------
// CSR build (graph fixed across rounds)
// ---------------------------------------------------------------------------
__global__ __launch_bounds__(256)
void csr_alloc_kernel(const int* __restrict__ cnt, int* __restrict__ off,
                      int* __restrict__ total, int N) {
    int v = blockIdx.x * 256 + threadIdx.x;
    int lane = threadIdx.x & 63;
    int c = (v < N) ? cnt[v] : 0;
    int s = c;
    #pragma unroll
    for (int d = 1; d < 64; d <<= 1) {
        int t = __shfl_up(s, d, 64);
        if (lane >= d) s += t;
    }
    int wave_total = __shfl(s, 63, 64);
    int base = 0;
    if (lane == 63) base = atomicAdd(total, wave_total);
    base = __shfl(base, 63, 64);
    if (v < N) off[v] = base + s - c;
}

__global__ __launch_bounds__(256)
void fill_csr_kernel(const int* __restrict__ src, const int* __restrict__ dst,
                     const int* __restrict__ off, int* __restrict__ cursor,
                     int* __restrict__ csr, int E) {
    int e = blockIdx.x * 256 + threadIdx.x;
    if (e >= E) return;
    int d = dst[e];
    int pos = atomicAdd(&cursor[d], 1);
    csr[off[d] + pos] = src[e];
}

// ---------------------------------------------------------------------------
// Gather-aggregate: 4 lane-groups x 16 lanes; 4 edges / load instruction;
// unroll 2 (R19-proven; unroll 4 cost ~4us on median-deg-8 loops).
// 2 shfl_xor reduce; 16B tiled c-write.
// ---------------------------------------------------------------------------
__global__ __launch_bounds__(256)
void agg_kernel(const bf16* __restrict__ SD, const int* __restrict__ csr,
                const int* __restrict__ off, const int* __restrict__ cnt,
                const float* __restrict__ b_msg, bf16* __restrict__ XT, int N) {
    const int v    = (blockIdx.x * 256 + threadIdx.x) >> 6;
    const int lane = threadIdx.x & 63;
    if (v >= N) return;
    const int g    = lane >> 4;     // edge-group 0..3
    const int sl   = lane & 15;     // 8-col slot
    const int deg  = cnt[v];
    const int base = off[v];

    float acc[8] = {};
    #pragma unroll 2
    for (int k = g; k < deg; k += 4) {
        int s0 = csr[base + k];
        bf16x8 row = *reinterpret_cast<const bf16x8*>(
            SD + (size_t)s0 * 256 + sl * 8);
        #pragma unroll
        for (int e = 0; e < 8; ++e) acc[e] += (float)row[e];
    }
    #pragma unroll
    for (int e = 0; e < 8; ++e) {
        acc[e] += __shfl_xor(acc[e], 16, 64);
        acc[e] += __shfl_xor(acc[e], 32, 64);
    }

    if (g != 0) return;
    bf16 outb[8];
    if (deg > 0) {
        const float inv = 1.0f / (float)deg;
        bf16x8 d8 = *reinterpret_cast<const bf16x8*>(
            SD + (size_t)v * 256 + 128 + sl * 8);
        const float4 b0 = *reinterpret_cast<const float4*>(b_msg + sl * 8);
        const float4 b1 = *reinterpret_cast<const float4*>(b_msg + sl * 8 + 4);
        const float bm[8] = {b0.x, b0.y, b0.z, b0.w, b1.x, b1.y, b1.z, b1.w};
        #pragma unroll
        for (int e = 0; e < 8; ++e)
            outb[e] = __float2bfloat16(acc[e] * inv + (float)d8[e] + bm[e]);
    } else {
        #pragma unroll
        for (int e = 0; e < 8; ++e) outb[e] = __float2bfloat16(0.0f);
    }
    bf16* dst = XT + ((size_t)(v >> 4) * 32 + 16 + sl) * 128 + (v & 15) * 8;
    *reinterpret_cast<float4*>(dst) = *reinterpret_cast<const float4*>(outb);
}

// ---------------------------------------------------------------------------
extern "C" void kernel_launch(void* const* d_in, const int* in_sizes, int n_in,
                              void* d_out, int out_size, void* d_ws, size_t ws_size,
                              hipStream_t stream) {
    const float* x     = (const float*)d_in[0];
    const float* h0    = (const float*)d_in[1];
    const float* W_msg = (const float*)d_in[2];
    const float* b_msg = (const float*)d_in[3];
    const float* w_ih  = (const float*)d_in[4];
    const float* w_hh  = (const float*)d_in[5];
    const float* b_ih  = (const float*)d_in[6];
    const float* b_hh  = (const float*)d_in[7];
    const int*   src   = (const int*)d_in[8];
    const int*   dst   = (const int*)d_in[9];
    float* h = (float*)d_out;

    char* ws = (char*)d_ws;
    size_t off_b = 0;
    auto alloc = [&](size_t bytes) -> void* {
        void* p = ws + off_b;
        off_b = (off_b + bytes + 255) & ~(size_t)255;
        return p;
    };
    int*   meta   = (int*)  alloc(((size_t)2 * N_NODES + 64) * 4);
    int*   cnt    = meta;
    int*   cursor = meta + N_NODES;
    int*   total  = meta + 2 * N_NODES;
    int*   off    = (int*)  alloc((size_t)N_NODES * 4);
    int*   csr    = (int*)  alloc((size_t)N_EDGES * 4);
    bf16*  Wsd_b  = (bf16*) alloc((size_t)WSD_N * 2);
    bf16*  Wg_b   = (bf16*) alloc((size_t)WG_N * 2);
    float* bg     = (float*)alloc(512 * 4);
    bf16*  XT     = (bf16*) alloc((size_t)NT * 32 * 128 * 2);   // 25.6MB
    bf16*  HT0    = (bf16*) alloc((size_t)NT * 16 * 128 * 2);   // 12.8MB
    bf16*  HT1    = (bf16*) alloc((size_t)NT * 16 * 128 * 2);   // 12.8MB
    bf16*  SD     = (bf16*) alloc((size_t)N_NODES * 256 * 2);

    // --- setup: memset -> fused(deg|prep|conv) -> csr alloc -> csr fill ---
    hipMemsetAsync(meta, 0, ((size_t)2 * N_NODES + 64) * 4, stream);
    const int SETUP_N = N_EDGES + PREP_N + N_NODES * 32;
    setup_kernel<<<(SETUP_N + 255) / 256, 256, 0, stream>>>(
        dst, cnt, W_msg, w_ih, w_hh, b_ih, b_hh, Wsd_b, Wg_b, bg,
        x, h0, XT, HT0);
    csr_alloc_kernel<<<(N_NODES + 255) / 256, 256, 0, stream>>>(cnt, off, total, N_NODES);
    fill_csr_kernel<<<(N_EDGES + 255) / 256, 256, 0, stream>>>(src, dst, off, cursor,
                                                               csr, N_EDGES);

    // XCD-aware 1D grids: 25 groups of (8 m-tiles x quads)
    const int SD_GRID    = 25 * 32;   // 800  (mt 0..199, bn 0..3)
    const int GATES_GRID = 25 * 64;   // 1600 (mt 0..199, q 0..7)
    const int AGG_GRID   = (N_NODES * 64 + 255) / 256;

    // ---- round 0: h = HT0 -> HT1 ----
    gemm_sd_kernel<<<SD_GRID, 256, 0, stream>>>(XT, HT0, Wsd_b, SD, N_NODES);
    agg_kernel<<<AGG_GRID, 256, 0, stream>>>(
        SD, csr, off, cnt, b_msg, XT, N_NODES);
    gates_kernel<0><<<GATES_GRID, 256, 0, stream>>>(
        XT, HT0, Wg_b, bg, nullptr, HT1, N_NODES);

    // ---- round 1 (final): h = HT1 -> d_out ----
    gemm_sd_kernel<<<SD_GRID, 256, 0, stream>>>(XT, HT1, Wsd_b, SD, N_NODES);
    agg_kernel<<<AGG_GRID, 256, 0, stream>>>(
        SD, csr, off, cnt, b_msg, XT, N_NODES);
    gates_kernel<1><<<GATES_GRID, 256, 0, stream>>>(
        XT, HT1, Wg_b, bg, h, nullptr, N_NODES);
}